// Round 10
// baseline (270.210 us; speedup 1.0000x reference)
//
#include <hip/hip_runtime.h>
#include <hip/hip_bf16.h>

typedef unsigned short u16;
typedef u16 us4 __attribute__((ext_vector_type(4)));
typedef u16 us8 __attribute__((ext_vector_type(8)));
typedef __bf16 bf16x8 __attribute__((ext_vector_type(8)));
typedef float f32x4 __attribute__((ext_vector_type(4)));

#define NDIM 4096
#define HDIM 2048

__device__ __forceinline__ u16 bfbits(float f) {
    __hip_bfloat16 h = __float2bfloat16(f);
    return __builtin_bit_cast(u16, h);
}
__device__ __forceinline__ float bf2f(u16 b) {
    return __builtin_bit_cast(float, ((unsigned)b) << 16);
}

__device__ __forceinline__ void gload_lds16(const u16* g, u16* l) {
    __builtin_amdgcn_global_load_lds((__attribute__((address_space(1))) void*)g,
                                     (__attribute__((address_space(3))) void*)l,
                                     16, 0, 0);
}

// ---------------------------------------------------------------------------
// Ce[u][k'] = cos(pi*k'*(u+0.5)/2048), Co[u][k'] = cos(pi*(2k'+1)*(u+0.5)/4096)
__global__ __launch_bounds__(256) void k_gencos2(u16* __restrict__ Ce, u16* __restrict__ Co) {
    int idx = blockIdx.x * 256 + threadIdx.x;
    int u = idx >> 8;
    int k0 = (idx & 255) * 8;
    unsigned step = (unsigned)(2 * u + 1);
    us8 e, o;
#pragma unroll
    for (int i = 0; i < 8; ++i) {
        unsigned kk = (unsigned)(k0 + i);
        unsigned te = (2u * kk * step) & 16383u;
        unsigned to = ((2u * kk + 1u) * step) & 16383u;
        e[i] = bfbits(cosf((float)te * 3.8349519697141029e-4f)); // 2pi/16384
        o[i] = bfbits(cosf((float)to * 3.8349519697141029e-4f));
    }
    *(us8*)&Ce[(size_t)idx * 8] = e;
    *(us8*)&Co[(size_t)idx * 8] = o;
}

// ---------------------------------------------------------------------------
// Xe[j][k'] = bf16(X[2k'][j]), Xo[j][k'] = bf16(X[2k'+1][j])
__global__ __launch_bounds__(256) void k_transpose_split(const float* __restrict__ X,
                                                         u16* __restrict__ Xe,
                                                         u16* __restrict__ Xo) {
    __shared__ float tile[64][65];
    int b  = blockIdx.x;
    int bx = (b & 63) * 64;
    int by = (b >> 6) * 64;
    int t  = threadIdx.x;
    int lr = t >> 4, lc = (t & 15) * 4;
#pragma unroll
    for (int r = 0; r < 64; r += 16) {
        float4 v = *(const float4*)&X[(size_t)(by + lr + r) * NDIM + bx + lc];
        tile[lr + r][lc + 0] = v.x;
        tile[lr + r][lc + 1] = v.y;
        tile[lr + r][lc + 2] = v.z;
        tile[lr + r][lc + 3] = v.w;
    }
    __syncthreads();
    int jl = t >> 2;
    int s8 = (t & 3) * 8;
    us8 e, o;
#pragma unroll
    for (int i = 0; i < 8; ++i) {
        e[i] = bfbits(tile[2 * (s8 + i)][jl]);
        o[i] = bfbits(tile[2 * (s8 + i) + 1][jl]);
    }
    size_t base = (size_t)(bx + jl) * HDIM + (by >> 1) + s8;
    *(us8*)&Xe[base] = e;
    *(us8*)&Xo[base] = o;
}

// ---------------------------------------------------------------------------
// Butterfly 1: W[u] = S[u]+D[u], W[4095-u] = S[u]-D[u], column-deinterleaved.
__global__ __launch_bounds__(256) void k_bfly1(const u16* __restrict__ S,
                                               const u16* __restrict__ D,
                                               u16* __restrict__ We,
                                               u16* __restrict__ Wo) {
    int idx = blockIdx.x * 256 + threadIdx.x;
    int u  = idx >> 9;
    int j0 = (idx & 511) * 8;
    us8 s8 = *(const us8*)&S[(size_t)u * NDIM + j0];
    us8 d8 = *(const us8*)&D[(size_t)u * NDIM + j0];
    us4 et, ot, eb, ob;
#pragma unroll
    for (int i = 0; i < 4; ++i) {
        float se = bf2f(s8[2 * i]),     de = bf2f(d8[2 * i]);
        float so = bf2f(s8[2 * i + 1]), dd = bf2f(d8[2 * i + 1]);
        et[i] = bfbits(se + de);  eb[i] = bfbits(se - de);
        ot[i] = bfbits(so + dd);  ob[i] = bfbits(so - dd);
    }
    size_t ct = (size_t)u * HDIM + (j0 >> 1);
    size_t cb = (size_t)(NDIM - 1 - u) * HDIM + (j0 >> 1);
    *(us4*)&We[ct] = et;  *(us4*)&Wo[ct] = ot;
    *(us4*)&We[cb] = eb;  *(us4*)&Wo[cb] = ob;
}

// ---------------------------------------------------------------------------
// Butterfly 2: Y[i][v'] = S2+D2, Y[i][4095-v'] = S2-D2, f32 out.
__global__ __launch_bounds__(256) void k_bfly2(const u16* __restrict__ S2,
                                               const u16* __restrict__ D2,
                                               float* __restrict__ Y) {
    int idx = blockIdx.x * 256 + threadIdx.x;
    int i  = idx >> 8;
    int v0 = (idx & 255) * 8;
    us8 s8 = *(const us8*)&S2[(size_t)i * HDIM + v0];
    us8 d8 = *(const us8*)&D2[(size_t)i * HDIM + v0];
    float sum[8], dif[8];
#pragma unroll
    for (int t = 0; t < 8; ++t) {
        float s = bf2f(s8[t]), d = bf2f(d8[t]);
        sum[t] = s + d;  dif[t] = s - d;
    }
    f32x4 a0, a1, r0, r1;
#pragma unroll
    for (int w = 0; w < 4; ++w) {
        a0[w] = sum[w];  a1[w] = sum[w + 4];
        r0[w] = dif[7 - w];  r1[w] = dif[3 - w];
    }
    float* row = Y + (size_t)i * NDIM;
    *(f32x4*)&row[v0]        = a0;
    *(f32x4*)&row[v0 + 4]    = a1;
    *(f32x4*)&row[4088 - v0] = r0;
    *(f32x4*)&row[4092 - v0] = r1;
}

// ---------------------------------------------------------------------------
// D = A @ B^T, 256x256 tile, BK=64, 8 waves, 8-phase schedule, 3-half-deep
// counted-vmcnt pipeline, one-phase-early ds_reads.
// r10 = r9 with the DETERMINISTIC bug fixed: A03 and A47 get SEPARATE
// register sets (aR0 / aR4) -- r8/r9's shared aR was overwritten at ph4-top
// (A03(t+1)) before ph4's MFMA consumed A47(t). Certification pattern (r9):
// WAITV(4) at ph3/ph7 post-MFMA, pre-BAR -> barrier makes it cross-wave.
// Per-acc arithmetic order unchanged (canary: absmax 64, bitwise = r7).
#define BAR() do { asm volatile("" ::: "memory"); __builtin_amdgcn_s_barrier(); \
                   asm volatile("" ::: "memory"); } while (0)
#define WAITV(N) asm volatile("s_waitcnt vmcnt(" #N ")" ::: "memory")

template <int NTK, int LOG_NTN>
__global__ __launch_bounds__(512, 2) void gemm256h(const u16* __restrict__ A0,
                                                   const u16* __restrict__ A1,
                                                   const u16* __restrict__ B0,
                                                   const u16* __restrict__ B1,
                                                   u16* __restrict__ out) {
    constexpr int KD  = NTK * 64;
    constexpr int NTN = 1 << LOG_NTN;
    constexpr int LDC = NTN * 256;
    constexpr int MTILES = 128 >> LOG_NTN;

    __shared__ u16 As[2 * 256 * 64];
    __shared__ u16 Bs[2 * 256 * 64];

    const int tid  = threadIdx.x;
    const int wave = tid >> 6;
    const int lane = tid & 63;

    const int bid = blockIdx.x;
    const int swz = (bid & 7) * 32 + (bid >> 3);   // grid 256, bijective
    const int half = swz >> 7;
    const int r    = swz & 127;
    const int bm   = (r >> LOG_NTN) * 256;
    const int bn   = (r & (NTN - 1)) * 256;

    const u16* A = half ? A1 : A0;
    const u16* B = half ? B1 : B0;
    u16* Cp = out + (size_t)half * MTILES * 256 * LDC;

    const int wr = wave >> 2;
    const int wc = wave & 3;

    const int srow = lane >> 3;
    const int scol = ((lane & 7) ^ srow) << 3;     // pre-swizzled global col offset

    const int fr   = lane & 15;
    const int hi   = lane >> 4;
    const int slot0 = ((hi)     ^ (lane & 7)) << 3;
    const int slot1 = ((hi + 4) ^ (lane & 7)) << 3;
    const int aRow = (wr * 128 + fr) * 64;
    const int bRow = (wc * 64 + fr) * 64;

    f32x4 acc[8][4] = {};
    bf16x8 aR0[4][2], aR4[4][2], b01a[2][2], b01b[2][2], b23[2][2];

#define STAGE_A(TK, H, BOFF)                                                     \
    do {                                                                         \
        const int _tk = (TK) & (NTK - 1);                                        \
        _Pragma("unroll")                                                        \
        for (int q = 0; q < 2; ++q) {                                            \
            const int seg  = wave * 2 + q;                                       \
            const int row0 = (H) * 64 + (seg & 7) * 8 + (seg >> 3) * 128;        \
            const u16* _g = A + (size_t)(bm + row0 + srow) * KD + _tk * 64 + scol; \
            gload_lds16(_g, As + (BOFF) + row0 * 64 + lane * 8);                 \
        }                                                                        \
    } while (0)

#define STAGE_B(TK, H, BOFF)                                                     \
    do {                                                                         \
        const int _tk = (TK) & (NTK - 1);                                        \
        _Pragma("unroll")                                                        \
        for (int q = 0; q < 2; ++q) {                                            \
            const int seg  = wave * 2 + q;                                       \
            const int row0 = (H) * 32 + (seg & 3) * 8 + (seg >> 2) * 64;         \
            const u16* _g = B + (size_t)(bn + row0 + srow) * KD + _tk * 64 + scol; \
            gload_lds16(_g, Bs + (BOFF) + row0 * 64 + lane * 8);                 \
        }                                                                        \
    } while (0)

#define LOAD_A(DST, MB, BOFF)                                                   \
    _Pragma("unroll")                                                           \
    for (int mm = 0; mm < 4; ++mm) {                                            \
        DST[mm][0] = __builtin_bit_cast(bf16x8, *(const us8*)(As + (BOFF) + aRow + ((MB) + mm) * 1024 + slot0)); \
        DST[mm][1] = __builtin_bit_cast(bf16x8, *(const us8*)(As + (BOFF) + aRow + ((MB) + mm) * 1024 + slot1)); \
    }

#define LOAD_B(DST, NB, BOFF)                                                   \
    _Pragma("unroll")                                                           \
    for (int nn = 0; nn < 2; ++nn) {                                            \
        DST[nn][0] = __builtin_bit_cast(bf16x8, *(const us8*)(Bs + (BOFF) + bRow + ((NB) + nn) * 1024 + slot0)); \
        DST[nn][1] = __builtin_bit_cast(bf16x8, *(const us8*)(Bs + (BOFF) + bRow + ((NB) + nn) * 1024 + slot1)); \
    }

#define MFMA_Q(MB, AREG, NB, BREG)                                              \
    do {                                                                        \
        __builtin_amdgcn_s_setprio(1);                                          \
        _Pragma("unroll")                                                       \
        for (int kk = 0; kk < 2; ++kk)                                          \
            _Pragma("unroll")                                                   \
            for (int mm = 0; mm < 4; ++mm)                                      \
                _Pragma("unroll")                                               \
                for (int nn = 0; nn < 2; ++nn)                                  \
                    acc[(MB)+mm][(NB)+nn] = __builtin_amdgcn_mfma_f32_16x16x32_bf16(AREG[mm][kk], BREG[nn][kk], acc[(MB)+mm][(NB)+nn], 0, 0, 0); \
        __builtin_amdgcn_s_setprio(0);                                          \
    } while (0)

    // ---- prologue: 7 halves (r4 ledger); WAITV(6)+BAR certifies tile 0;
    //      pre-read ph1 operands (A03(0) -> aR0, B01(0) -> b01a, buf0)
    STAGE_B(0, 0, 0);
    STAGE_A(0, 0, 0);
    STAGE_B(0, 1, 0);
    STAGE_A(0, 1, 0);
    STAGE_B(1, 0, 16384);
    STAGE_A(1, 0, 16384);
    STAGE_B(1, 1, 16384);
    WAITV(6);
    BAR();
    LOAD_A(aR0, 0, 0);
    LOAD_B(b01a, 0, 0);

    for (int t = 0; t < NTK; t += 2) {
        // ph1: read B23(t)->b23 [ph2/3]; stage A(t+1)h1'->buf1; MFMA(m0-3,n0-1)
        LOAD_B(b23, 2, 0);
        STAGE_A(t + 1, 1, 16384);
        BAR();
        MFMA_Q(0, aR0, 0, b01a);
        BAR();
        // ph2: read A47(t)->aR4 [ph3/4]; stage B(t+2)h0'->buf0; MFMA(m0-3,n2-3)
        LOAD_A(aR4, 4, 0);
        STAGE_B(t + 2, 0, 0);
        BAR();
        MFMA_Q(0, aR0, 2, b23);
        BAR();
        // ph3: no reads; stage A(t+2)h0'->buf0; MFMA(m4-7,n2-3);
        //      WAITV(4)+BAR certifies tile t+1 (buf1) for ALL waves
        STAGE_A(t + 2, 0, 0);
        BAR();
        MFMA_Q(4, aR4, 2, b23);
        WAITV(4);
        BAR();
        // ph4: read A03(t+1)->aR0 + B01(t+1)->b01b from buf1 (certified);
        //      stage B(t+2)h1'->buf0; MFMA(m4-7,n0-1) uses aR4(t)+b01a(t)
        LOAD_A(aR0, 0, 16384);
        LOAD_B(b01b, 0, 16384);
        STAGE_B(t + 2, 1, 0);
        BAR();
        MFMA_Q(4, aR4, 0, b01a);
        BAR();
        // ph5: read B23(t+1)->b23; stage A(t+2)h1'->buf0; MFMA(m0-3,n0-1) b01b
        LOAD_B(b23, 2, 16384);
        STAGE_A(t + 2, 1, 0);
        BAR();
        MFMA_Q(0, aR0, 0, b01b);
        BAR();
        // ph6: read A47(t+1)->aR4; stage B(t+3)h0'->buf1; MFMA(m0-3,n2-3)
        LOAD_A(aR4, 4, 16384);
        STAGE_B(t + 3, 0, 16384);
        BAR();
        MFMA_Q(0, aR0, 2, b23);
        BAR();
        // ph7: no reads; stage A(t+3)h0'->buf1; MFMA(m4-7,n2-3);
        //      WAITV(4)+BAR certifies tile t+2 (buf0)
        STAGE_A(t + 3, 0, 16384);
        BAR();
        MFMA_Q(4, aR4, 2, b23);
        WAITV(4);
        BAR();
        // ph8: read A03(t+2)->aR0 + B01(t+2)->b01a from buf0 (certified);
        //      stage B(t+3)h1'->buf1; MFMA(m4-7,n0-1) uses aR4(t+1)+b01b(t+1)
        LOAD_A(aR0, 0, 0);
        LOAD_B(b01a, 0, 0);
        STAGE_B(t + 3, 1, 16384);
        BAR();
        MFMA_Q(4, aR4, 0, b01b);
        BAR();
    }

    asm volatile("s_waitcnt vmcnt(0)" ::: "memory");

    const int orow0 = wr * 128 + hi * 4;
    const int ocol0 = bn + wc * 64 + fr;
#pragma unroll
    for (int m = 0; m < 8; ++m)
#pragma unroll
        for (int n = 0; n < 4; ++n) {
            f32x4 v = acc[m][n];
#pragma unroll
            for (int rr = 0; rr < 4; ++rr) {
                size_t off = (size_t)(bm + orow0 + m * 16 + rr) * LDC + (ocol0 + n * 16);
                Cp[off] = bfbits(v[rr]);
            }
        }
#undef STAGE_A
#undef STAGE_B
#undef LOAD_A
#undef LOAD_B
#undef MFMA_Q
}

// ---------------------------------------------------------------------------
extern "C" void kernel_launch(void* const* d_in, const int* in_sizes, int n_in,
                              void* d_out, int out_size, void* d_ws, size_t ws_size,
                              hipStream_t stream) {
    const float* X = (const float*)d_in[0];
    float* Y = (float*)d_out;

    const size_t QM = (size_t)HDIM * HDIM;
    u16* Ce = (u16*)d_ws;
    u16* Co = Ce + QM;
    u16* Xe = Co + QM;
    u16* Xo = Xe + 2 * QM;
    u16* S  = Xo + 2 * QM;
    u16* D  = S + 2 * QM;
    u16* We = Xe;
    u16* Wo = Xo;
    u16* S2 = S;
    u16* D2 = D;

    k_gencos2<<<2048, 256, 0, stream>>>(Ce, Co);
    k_transpose_split<<<4096, 256, 0, stream>>>(X, Xe, Xo);
    gemm256h<32, 4><<<256, 512, 0, stream>>>(Ce, Co, Xe, Xo, S);
    k_bfly1<<<4096, 256, 0, stream>>>(S, D, We, Wo);
    gemm256h<32, 3><<<256, 512, 0, stream>>>(We, Wo, Ce, Co, S2);
    k_bfly2<<<4096, 256, 0, stream>>>(S2, D2, Y);
}

// Round 11
// 187.783 us; speedup vs baseline: 1.4390x; 1.4390x over previous
//
#include <hip/hip_runtime.h>
#include <hip/hip_bf16.h>

typedef unsigned short u16;
typedef u16 us4 __attribute__((ext_vector_type(4)));
typedef u16 us8 __attribute__((ext_vector_type(8)));
typedef __bf16 bf16x8 __attribute__((ext_vector_type(8)));
typedef float f32x4 __attribute__((ext_vector_type(4)));
typedef float f32x16 __attribute__((ext_vector_type(16)));

#define NDIM 4096
#define HDIM 2048

__device__ __forceinline__ u16 bfbits(float f) {
    __hip_bfloat16 h = __float2bfloat16(f);
    return __builtin_bit_cast(u16, h);
}
__device__ __forceinline__ float bf2f(u16 b) {
    return __builtin_bit_cast(float, ((unsigned)b) << 16);
}

__device__ __forceinline__ void gload_lds16(const u16* g, u16* l) {
    __builtin_amdgcn_global_load_lds((__attribute__((address_space(1))) void*)g,
                                     (__attribute__((address_space(3))) void*)l,
                                     16, 0, 0);
}

// ---------------------------------------------------------------------------
// Ce[u][k'] = cos(pi*k'*(u+0.5)/2048), Co[u][k'] = cos(pi*(2k'+1)*(u+0.5)/4096)
__global__ __launch_bounds__(256) void k_gencos2(u16* __restrict__ Ce, u16* __restrict__ Co) {
    int idx = blockIdx.x * 256 + threadIdx.x;
    int u = idx >> 8;
    int k0 = (idx & 255) * 8;
    unsigned step = (unsigned)(2 * u + 1);
    us8 e, o;
#pragma unroll
    for (int i = 0; i < 8; ++i) {
        unsigned kk = (unsigned)(k0 + i);
        unsigned te = (2u * kk * step) & 16383u;
        unsigned to = ((2u * kk + 1u) * step) & 16383u;
        e[i] = bfbits(cosf((float)te * 3.8349519697141029e-4f)); // 2pi/16384
        o[i] = bfbits(cosf((float)to * 3.8349519697141029e-4f));
    }
    *(us8*)&Ce[(size_t)idx * 8] = e;
    *(us8*)&Co[(size_t)idx * 8] = o;
}

// ---------------------------------------------------------------------------
// Xe[j][k'] = bf16(X[2k'][j]), Xo[j][k'] = bf16(X[2k'+1][j])
__global__ __launch_bounds__(256) void k_transpose_split(const float* __restrict__ X,
                                                         u16* __restrict__ Xe,
                                                         u16* __restrict__ Xo) {
    __shared__ float tile[64][65];
    int b  = blockIdx.x;
    int bx = (b & 63) * 64;
    int by = (b >> 6) * 64;
    int t  = threadIdx.x;
    int lr = t >> 4, lc = (t & 15) * 4;
#pragma unroll
    for (int r = 0; r < 64; r += 16) {
        float4 v = *(const float4*)&X[(size_t)(by + lr + r) * NDIM + bx + lc];
        tile[lr + r][lc + 0] = v.x;
        tile[lr + r][lc + 1] = v.y;
        tile[lr + r][lc + 2] = v.z;
        tile[lr + r][lc + 3] = v.w;
    }
    __syncthreads();
    int jl = t >> 2;
    int s8 = (t & 3) * 8;
    us8 e, o;
#pragma unroll
    for (int i = 0; i < 8; ++i) {
        e[i] = bfbits(tile[2 * (s8 + i)][jl]);
        o[i] = bfbits(tile[2 * (s8 + i) + 1][jl]);
    }
    size_t base = (size_t)(bx + jl) * HDIM + (by >> 1) + s8;
    *(us8*)&Xe[base] = e;
    *(us8*)&Xo[base] = o;
}

// ---------------------------------------------------------------------------
// Butterfly 1: W[u] = S[u]+D[u], W[4095-u] = S[u]-D[u], column-deinterleaved.
__global__ __launch_bounds__(256) void k_bfly1(const u16* __restrict__ S,
                                               const u16* __restrict__ D,
                                               u16* __restrict__ We,
                                               u16* __restrict__ Wo) {
    int idx = blockIdx.x * 256 + threadIdx.x;
    int u  = idx >> 9;
    int j0 = (idx & 511) * 8;
    us8 s8 = *(const us8*)&S[(size_t)u * NDIM + j0];
    us8 d8 = *(const us8*)&D[(size_t)u * NDIM + j0];
    us4 et, ot, eb, ob;
#pragma unroll
    for (int i = 0; i < 4; ++i) {
        float se = bf2f(s8[2 * i]),     de = bf2f(d8[2 * i]);
        float so = bf2f(s8[2 * i + 1]), dd = bf2f(d8[2 * i + 1]);
        et[i] = bfbits(se + de);  eb[i] = bfbits(se - de);
        ot[i] = bfbits(so + dd);  ob[i] = bfbits(so - dd);
    }
    size_t ct = (size_t)u * HDIM + (j0 >> 1);
    size_t cb = (size_t)(NDIM - 1 - u) * HDIM + (j0 >> 1);
    *(us4*)&We[ct] = et;  *(us4*)&Wo[ct] = ot;
    *(us4*)&We[cb] = eb;  *(us4*)&Wo[cb] = ob;
}

// ---------------------------------------------------------------------------
// Butterfly 2: Y[i][v'] = S2+D2, Y[i][4095-v'] = S2-D2, f32 out.
__global__ __launch_bounds__(256) void k_bfly2(const u16* __restrict__ S2,
                                               const u16* __restrict__ D2,
                                               float* __restrict__ Y) {
    int idx = blockIdx.x * 256 + threadIdx.x;
    int i  = idx >> 8;
    int v0 = (idx & 255) * 8;
    us8 s8 = *(const us8*)&S2[(size_t)i * HDIM + v0];
    us8 d8 = *(const us8*)&D2[(size_t)i * HDIM + v0];
    float sum[8], dif[8];
#pragma unroll
    for (int t = 0; t < 8; ++t) {
        float s = bf2f(s8[t]), d = bf2f(d8[t]);
        sum[t] = s + d;  dif[t] = s - d;
    }
    f32x4 a0, a1, r0, r1;
#pragma unroll
    for (int w = 0; w < 4; ++w) {
        a0[w] = sum[w];  a1[w] = sum[w + 4];
        r0[w] = dif[7 - w];  r1[w] = dif[3 - w];
    }
    float* row = Y + (size_t)i * NDIM;
    *(f32x4*)&row[v0]        = a0;
    *(f32x4*)&row[v0 + 4]    = a1;
    *(f32x4*)&row[4088 - v0] = r0;
    *(f32x4*)&row[4092 - v0] = r1;
}

// ---------------------------------------------------------------------------
// D = A @ B^T, 256x256 tile, BK=64, 8 waves, 8-phase schedule, 3-half-deep
// counted-vmcnt pipeline. r11 = EXACT r7 skeleton (stage ledger, sync, read
// placement, quadrant order) with the MFMA shape swapped to 32x32x16:
// per wave 128x64 = 4x2 tiles of 32^2, acc = 8 x f32x16. Per-quadrant reads
// stay 8 A + 4 B ds_read_b128 (same geometry, reinterpreted). A/B frag:
// row|col = lane&31, k = (lane>>5)*8 + j (any consistent bijective k-map is
// valid since A,B share it). C/D: col=lane&31, row=(reg&3)+8*(reg>>2)+
// 4*(lane>>5) [guide m74/m101].
#define BAR() do { asm volatile("" ::: "memory"); __builtin_amdgcn_s_barrier(); \
                   asm volatile("" ::: "memory"); } while (0)
#define WAITV(N) asm volatile("s_waitcnt vmcnt(" #N ")" ::: "memory")

template <int NTK, int LOG_NTN>
__global__ __launch_bounds__(512, 2) void gemm256h(const u16* __restrict__ A0,
                                                   const u16* __restrict__ A1,
                                                   const u16* __restrict__ B0,
                                                   const u16* __restrict__ B1,
                                                   u16* __restrict__ out) {
    constexpr int KD  = NTK * 64;
    constexpr int NTN = 1 << LOG_NTN;
    constexpr int LDC = NTN * 256;
    constexpr int MTILES = 128 >> LOG_NTN;

    __shared__ u16 As[2 * 256 * 64];
    __shared__ u16 Bs[2 * 256 * 64];

    const int tid  = threadIdx.x;
    const int wave = tid >> 6;
    const int lane = tid & 63;

    const int bid = blockIdx.x;
    const int swz = (bid & 7) * 32 + (bid >> 3);   // grid 256, bijective
    const int half = swz >> 7;
    const int r    = swz & 127;
    const int bm   = (r >> LOG_NTN) * 256;
    const int bn   = (r & (NTN - 1)) * 256;

    const u16* A = half ? A1 : A0;
    const u16* B = half ? B1 : B0;
    u16* Cp = out + (size_t)half * MTILES * 256 * LDC;

    const int wr = wave >> 2;    // 0..1 -> 128-row band
    const int wc = wave & 3;     // 0..3 -> 64-col band

    const int srow = lane >> 3;
    const int scol = ((lane & 7) ^ srow) << 3;     // pre-swizzled global col offset

    const int l31  = lane & 31;
    const int hi32 = lane >> 5;
    // swizzled 16B-slot byte offsets for k-subtile ks (global slot 2ks+hi32)
    const int sl0 = ((0 + hi32) ^ (lane & 7)) << 3;
    const int sl1 = ((2 + hi32) ^ (lane & 7)) << 3;
    const int sl2 = ((4 + hi32) ^ (lane & 7)) << 3;
    const int sl3 = ((6 + hi32) ^ (lane & 7)) << 3;
    const int aRow = (wr * 128 + l31) * 64;   // + mt*2048
    const int bRow = (wc * 64 + l31) * 64;    // + nt*2048

    f32x16 acc[4][2] = {};                    // [m-tile][n-tile]
    bf16x8 aR[2][4], b0[4], b1[4];            // [mt][ks], [ks]

#define STAGE_A(TK, H, BOFF)                                                     \
    do {                                                                         \
        const int _tk = (TK) & (NTK - 1);                                        \
        _Pragma("unroll")                                                        \
        for (int q = 0; q < 2; ++q) {                                            \
            const int seg  = wave * 2 + q;                                       \
            const int row0 = (H) * 64 + (seg & 7) * 8 + (seg >> 3) * 128;        \
            const u16* _g = A + (size_t)(bm + row0 + srow) * KD + _tk * 64 + scol; \
            gload_lds16(_g, As + (BOFF) + row0 * 64 + lane * 8);                 \
        }                                                                        \
    } while (0)

#define STAGE_B(TK, H, BOFF)                                                     \
    do {                                                                         \
        const int _tk = (TK) & (NTK - 1);                                        \
        _Pragma("unroll")                                                        \
        for (int q = 0; q < 2; ++q) {                                            \
            const int seg  = wave * 2 + q;                                       \
            const int row0 = (H) * 32 + (seg & 3) * 8 + (seg >> 2) * 64;         \
            const u16* _g = B + (size_t)(bn + row0 + srow) * KD + _tk * 64 + scol; \
            gload_lds16(_g, Bs + (BOFF) + row0 * 64 + lane * 8);                 \
        }                                                                        \
    } while (0)

// read 2 m-tiles (MB, MB+1) x 4 k-subtiles into aR  (8 x ds_read_b128)
#define LOAD_A(MB, BOFF)                                                        \
    do {                                                                        \
        aR[0][0] = __builtin_bit_cast(bf16x8, *(const us8*)(As + (BOFF) + aRow + ((MB) + 0) * 2048 + sl0)); \
        aR[0][1] = __builtin_bit_cast(bf16x8, *(const us8*)(As + (BOFF) + aRow + ((MB) + 0) * 2048 + sl1)); \
        aR[0][2] = __builtin_bit_cast(bf16x8, *(const us8*)(As + (BOFF) + aRow + ((MB) + 0) * 2048 + sl2)); \
        aR[0][3] = __builtin_bit_cast(bf16x8, *(const us8*)(As + (BOFF) + aRow + ((MB) + 0) * 2048 + sl3)); \
        aR[1][0] = __builtin_bit_cast(bf16x8, *(const us8*)(As + (BOFF) + aRow + ((MB) + 1) * 2048 + sl0)); \
        aR[1][1] = __builtin_bit_cast(bf16x8, *(const us8*)(As + (BOFF) + aRow + ((MB) + 1) * 2048 + sl1)); \
        aR[1][2] = __builtin_bit_cast(bf16x8, *(const us8*)(As + (BOFF) + aRow + ((MB) + 1) * 2048 + sl2)); \
        aR[1][3] = __builtin_bit_cast(bf16x8, *(const us8*)(As + (BOFF) + aRow + ((MB) + 1) * 2048 + sl3)); \
    } while (0)

// read 1 n-tile x 4 k-subtiles into DST  (4 x ds_read_b128)
#define LOAD_B(DST, NT, BOFF)                                                   \
    do {                                                                        \
        DST[0] = __builtin_bit_cast(bf16x8, *(const us8*)(Bs + (BOFF) + bRow + (NT) * 2048 + sl0)); \
        DST[1] = __builtin_bit_cast(bf16x8, *(const us8*)(Bs + (BOFF) + bRow + (NT) * 2048 + sl1)); \
        DST[2] = __builtin_bit_cast(bf16x8, *(const us8*)(Bs + (BOFF) + bRow + (NT) * 2048 + sl2)); \
        DST[3] = __builtin_bit_cast(bf16x8, *(const us8*)(Bs + (BOFF) + bRow + (NT) * 2048 + sl3)); \
    } while (0)

// quadrant: 2 m-tiles (MB, MB+1) x 1 n-tile NT x 4 k-subtiles = 8 MFMAs
#define MFMA_Q(MB, NT, BREG)                                                    \
    do {                                                                        \
        __builtin_amdgcn_s_setprio(1);                                          \
        _Pragma("unroll")                                                       \
        for (int ks = 0; ks < 4; ++ks)                                          \
            _Pragma("unroll")                                                   \
            for (int mm = 0; mm < 2; ++mm)                                      \
                acc[(MB)+mm][NT] = __builtin_amdgcn_mfma_f32_32x32x16_bf16(aR[mm][ks], BREG[ks], acc[(MB)+mm][NT], 0, 0, 0); \
        __builtin_amdgcn_s_setprio(0);                                          \
    } while (0)

    // ---- prologue: 7 halves (r4 ledger); vmcnt(6)+BAR certifies tile 0
    STAGE_B(0, 0, 0);
    STAGE_A(0, 0, 0);
    STAGE_B(0, 1, 0);
    STAGE_A(0, 1, 0);
    STAGE_B(1, 0, 16384);
    STAGE_A(1, 0, 16384);
    STAGE_B(1, 1, 16384);
    WAITV(6);
    BAR();

    for (int t = 0; t < NTK; t += 2) {
        // ph1: q(mt01, nt0); stage A(t+1)h1' -> buf1
        LOAD_A(0, 0);
        LOAD_B(b0, 0, 0);
        STAGE_A(t + 1, 1, 16384);
        BAR();
        MFMA_Q(0, 0, b0);
        BAR();
        // ph2: q(mt01, nt1); stage B(t+2)h0' -> buf0
        LOAD_B(b1, 1, 0);
        STAGE_B(t + 2, 0, 0);
        BAR();
        MFMA_Q(0, 1, b1);
        BAR();
        // ph3: q(mt23, nt1); stage A(t+2)h0' -> buf0
        LOAD_A(2, 0);
        STAGE_A(t + 2, 0, 0);
        BAR();
        MFMA_Q(2, 1, b1);
        BAR();
        // ph4: q(mt23, nt0); stage B(t+2)h1' -> buf0; vmcnt(6) completes tile t+1
        STAGE_B(t + 2, 1, 0);
        BAR();
        MFMA_Q(2, 0, b0);
        WAITV(6);
        BAR();
        // ph5: tile t+1 (buf1) q(mt01, nt0); stage A(t+2)h1' -> buf0
        LOAD_A(0, 16384);
        LOAD_B(b0, 0, 16384);
        STAGE_A(t + 2, 1, 0);
        BAR();
        MFMA_Q(0, 0, b0);
        BAR();
        // ph6: q(mt01, nt1); stage B(t+3)h0' -> buf1
        LOAD_B(b1, 1, 16384);
        STAGE_B(t + 3, 0, 16384);
        BAR();
        MFMA_Q(0, 1, b1);
        BAR();
        // ph7: q(mt23, nt1); stage A(t+3)h0' -> buf1
        LOAD_A(2, 16384);
        STAGE_A(t + 3, 0, 16384);
        BAR();
        MFMA_Q(2, 1, b1);
        BAR();
        // ph8: q(mt23, nt0); stage B(t+3)h1' -> buf1; vmcnt(6) completes tile t+2
        STAGE_B(t + 3, 1, 16384);
        BAR();
        MFMA_Q(2, 0, b0);
        WAITV(6);
        BAR();
    }

    asm volatile("s_waitcnt vmcnt(0)" ::: "memory");

    // epilogue: 32x32 C/D layout col=lane&31, row=(reg&3)+8*(reg>>2)+4*(lane>>5)
    const int orow0 = bm + wr * 128 + 4 * hi32;
    const int ocol0 = bn + wc * 64 + l31;
#pragma unroll
    for (int mt = 0; mt < 4; ++mt)
#pragma unroll
        for (int nt = 0; nt < 2; ++nt) {
            f32x16 v = acc[mt][nt];
#pragma unroll
            for (int rg = 0; rg < 16; ++rg) {
                int row = orow0 + mt * 32 + (rg & 3) + 8 * (rg >> 2);
                size_t off = (size_t)row * LDC + (ocol0 + nt * 32);
                Cp[off] = bfbits(v[rg]);
            }
        }
#undef STAGE_A
#undef STAGE_B
#undef LOAD_A
#undef LOAD_B
#undef MFMA_Q
}

// ---------------------------------------------------------------------------
extern "C" void kernel_launch(void* const* d_in, const int* in_sizes, int n_in,
                              void* d_out, int out_size, void* d_ws, size_t ws_size,
                              hipStream_t stream) {
    const float* X = (const float*)d_in[0];
    float* Y = (float*)d_out;

    const size_t QM = (size_t)HDIM * HDIM;
    u16* Ce = (u16*)d_ws;
    u16* Co = Ce + QM;
    u16* Xe = Co + QM;
    u16* Xo = Xe + 2 * QM;
    u16* S  = Xo + 2 * QM;
    u16* D  = S + 2 * QM;
    u16* We = Xe;
    u16* Wo = Xo;
    u16* S2 = S;
    u16* D2 = D;

    k_gencos2<<<2048, 256, 0, stream>>>(Ce, Co);
    k_transpose_split<<<4096, 256, 0, stream>>>(X, Xe, Xo);
    gemm256h<32, 4><<<256, 512, 0, stream>>>(Ce, Co, Xe, Xo, S);
    k_bfly1<<<4096, 256, 0, stream>>>(S, D, We, Wo);
    gemm256h<32, 3><<<256, 512, 0, stream>>>(We, Wo, Ce, Co, S2);
    k_bfly2<<<4096, 256, 0, stream>>>(S2, D2, Y);
}

// Round 12
// 170.880 us; speedup vs baseline: 1.5813x; 1.0989x over previous
//
#include <hip/hip_runtime.h>
#include <hip/hip_bf16.h>

typedef unsigned short u16;
typedef u16 us4 __attribute__((ext_vector_type(4)));
typedef u16 us8 __attribute__((ext_vector_type(8)));
typedef __bf16 bf16x8 __attribute__((ext_vector_type(8)));
typedef float f32x4 __attribute__((ext_vector_type(4)));

#define NDIM 4096
#define HDIM 2048

__device__ __forceinline__ u16 bfbits(float f) {
    __hip_bfloat16 h = __float2bfloat16(f);
    return __builtin_bit_cast(u16, h);
}
__device__ __forceinline__ float bf2f(u16 b) {
    return __builtin_bit_cast(float, ((unsigned)b) << 16);
}

__device__ __forceinline__ void gload_lds16(const u16* g, u16* l) {
    __builtin_amdgcn_global_load_lds((__attribute__((address_space(1))) void*)g,
                                     (__attribute__((address_space(3))) void*)l,
                                     16, 0, 0);
}

// ---------------------------------------------------------------------------
// Fused prep: blocks [0,2048) generate cos tables; blocks [2048,6144) do the
// transpose+split of X. Independent outputs; co-residency overlaps gencos's
// VALU work with the transpose's HBM traffic.
__global__ __launch_bounds__(256) void k_prep(u16* __restrict__ Ce, u16* __restrict__ Co,
                                              const float* __restrict__ X,
                                              u16* __restrict__ Xe, u16* __restrict__ Xo) {
    __shared__ float tile[64][65];
    if (blockIdx.x < 2048) {
        // --- gencos2: Ce[u][k'] = cos(pi*2k'*(u+.5)/4096), Co odd
        int idx = blockIdx.x * 256 + threadIdx.x;
        int u = idx >> 8;
        int k0 = (idx & 255) * 8;
        unsigned step = (unsigned)(2 * u + 1);
        us8 e, o;
#pragma unroll
        for (int i = 0; i < 8; ++i) {
            unsigned kk = (unsigned)(k0 + i);
            unsigned te = (2u * kk * step) & 16383u;
            unsigned to = ((2u * kk + 1u) * step) & 16383u;
            e[i] = bfbits(cosf((float)te * 3.8349519697141029e-4f)); // 2pi/16384
            o[i] = bfbits(cosf((float)to * 3.8349519697141029e-4f));
        }
        *(us8*)&Ce[(size_t)idx * 8] = e;
        *(us8*)&Co[(size_t)idx * 8] = o;
    } else {
        // --- transpose_split: Xe[j][k'] = bf16(X[2k'][j]), Xo odd
        int b  = blockIdx.x - 2048;
        int bx = (b & 63) * 64;
        int by = (b >> 6) * 64;
        int t  = threadIdx.x;
        int lr = t >> 4, lc = (t & 15) * 4;
#pragma unroll
        for (int r = 0; r < 64; r += 16) {
            float4 v = *(const float4*)&X[(size_t)(by + lr + r) * NDIM + bx + lc];
            tile[lr + r][lc + 0] = v.x;
            tile[lr + r][lc + 1] = v.y;
            tile[lr + r][lc + 2] = v.z;
            tile[lr + r][lc + 3] = v.w;
        }
        __syncthreads();
        int jl = t >> 2;
        int s8 = (t & 3) * 8;
        us8 e, o;
#pragma unroll
        for (int i = 0; i < 8; ++i) {
            e[i] = bfbits(tile[2 * (s8 + i)][jl]);
            o[i] = bfbits(tile[2 * (s8 + i) + 1][jl]);
        }
        size_t base = (size_t)(bx + jl) * HDIM + (by >> 1) + s8;
        *(us8*)&Xe[base] = e;
        *(us8*)&Xo[base] = o;
    }
}

// ---------------------------------------------------------------------------
// Butterfly 1: W[u] = S[u]+D[u], W[4095-u] = S[u]-D[u], column-deinterleaved.
__global__ __launch_bounds__(256) void k_bfly1(const u16* __restrict__ S,
                                               const u16* __restrict__ D,
                                               u16* __restrict__ We,
                                               u16* __restrict__ Wo) {
    int idx = blockIdx.x * 256 + threadIdx.x;
    int u  = idx >> 9;
    int j0 = (idx & 511) * 8;
    us8 s8 = *(const us8*)&S[(size_t)u * NDIM + j0];
    us8 d8 = *(const us8*)&D[(size_t)u * NDIM + j0];
    us4 et, ot, eb, ob;
#pragma unroll
    for (int i = 0; i < 4; ++i) {
        float se = bf2f(s8[2 * i]),     de = bf2f(d8[2 * i]);
        float so = bf2f(s8[2 * i + 1]), dd = bf2f(d8[2 * i + 1]);
        et[i] = bfbits(se + de);  eb[i] = bfbits(se - de);
        ot[i] = bfbits(so + dd);  ob[i] = bfbits(so - dd);
    }
    size_t ct = (size_t)u * HDIM + (j0 >> 1);
    size_t cb = (size_t)(NDIM - 1 - u) * HDIM + (j0 >> 1);
    *(us4*)&We[ct] = et;  *(us4*)&Wo[ct] = ot;
    *(us4*)&We[cb] = eb;  *(us4*)&Wo[cb] = ob;
}

// ---------------------------------------------------------------------------
// Butterfly 2: Y[i][v'] = S2+D2, Y[i][4095-v'] = S2-D2, f32 out.
__global__ __launch_bounds__(256) void k_bfly2(const u16* __restrict__ S2,
                                               const u16* __restrict__ D2,
                                               float* __restrict__ Y) {
    int idx = blockIdx.x * 256 + threadIdx.x;
    int i  = idx >> 8;
    int v0 = (idx & 255) * 8;
    us8 s8 = *(const us8*)&S2[(size_t)i * HDIM + v0];
    us8 d8 = *(const us8*)&D2[(size_t)i * HDIM + v0];
    float sum[8], dif[8];
#pragma unroll
    for (int t = 0; t < 8; ++t) {
        float s = bf2f(s8[t]), d = bf2f(d8[t]);
        sum[t] = s + d;  dif[t] = s - d;
    }
    f32x4 a0, a1, r0, r1;
#pragma unroll
    for (int w = 0; w < 4; ++w) {
        a0[w] = sum[w];  a1[w] = sum[w + 4];
        r0[w] = dif[7 - w];  r1[w] = dif[3 - w];
    }
    float* row = Y + (size_t)i * NDIM;
    *(f32x4*)&row[v0]        = a0;
    *(f32x4*)&row[v0 + 4]    = a1;
    *(f32x4*)&row[4088 - v0] = r0;
    *(f32x4*)&row[4092 - v0] = r1;
}

// ---------------------------------------------------------------------------
// D = A @ B^T, 256x256 tile, BK=64, 8 waves, 8-phase schedule, 3-half-deep
// counted-vmcnt pipeline. r12 = exact r7 structure (66.0us known-good) +
// lgkmcnt(8) pre-barrier throttle in the 12-read phases (ph1/ph5) -- the
// m201 template's optional line. Timing-only edit; bitwise-same output.
#define BAR() do { asm volatile("" ::: "memory"); __builtin_amdgcn_s_barrier(); \
                   asm volatile("" ::: "memory"); } while (0)
#define WAITV(N) asm volatile("s_waitcnt vmcnt(" #N ")" ::: "memory")
#define THROTTLE() asm volatile("s_waitcnt lgkmcnt(8)" ::: "memory")

template <int NTK, int LOG_NTN>
__global__ __launch_bounds__(512, 2) void gemm256h(const u16* __restrict__ A0,
                                                   const u16* __restrict__ A1,
                                                   const u16* __restrict__ B0,
                                                   const u16* __restrict__ B1,
                                                   u16* __restrict__ out) {
    constexpr int KD  = NTK * 64;
    constexpr int NTN = 1 << LOG_NTN;
    constexpr int LDC = NTN * 256;
    constexpr int MTILES = 128 >> LOG_NTN;

    __shared__ u16 As[2 * 256 * 64];
    __shared__ u16 Bs[2 * 256 * 64];

    const int tid  = threadIdx.x;
    const int wave = tid >> 6;
    const int lane = tid & 63;

    const int bid = blockIdx.x;
    const int swz = (bid & 7) * 32 + (bid >> 3);   // grid 256, bijective
    const int half = swz >> 7;
    const int r    = swz & 127;
    const int bm   = (r >> LOG_NTN) * 256;
    const int bn   = (r & (NTN - 1)) * 256;

    const u16* A = half ? A1 : A0;
    const u16* B = half ? B1 : B0;
    u16* Cp = out + (size_t)half * MTILES * 256 * LDC;

    const int wr = wave >> 2;
    const int wc = wave & 3;

    const int srow = lane >> 3;
    const int scol = ((lane & 7) ^ srow) << 3;     // pre-swizzled global col offset

    const int fr   = lane & 15;
    const int hi   = lane >> 4;
    const int slot0 = ((hi)     ^ (lane & 7)) << 3;
    const int slot1 = ((hi + 4) ^ (lane & 7)) << 3;
    const int aRow = (wr * 128 + fr) * 64;
    const int bRow = (wc * 64 + fr) * 64;

    f32x4 acc[8][4] = {};
    bf16x8 aR[4][2], b01[2][2], b23[2][2];

#define STAGE_A(TK, H, BOFF)                                                     \
    do {                                                                         \
        const int _tk = (TK) & (NTK - 1);                                        \
        _Pragma("unroll")                                                        \
        for (int q = 0; q < 2; ++q) {                                            \
            const int seg  = wave * 2 + q;                                       \
            const int row0 = (H) * 64 + (seg & 7) * 8 + (seg >> 3) * 128;        \
            const u16* _g = A + (size_t)(bm + row0 + srow) * KD + _tk * 64 + scol; \
            gload_lds16(_g, As + (BOFF) + row0 * 64 + lane * 8);                 \
        }                                                                        \
    } while (0)

#define STAGE_B(TK, H, BOFF)                                                     \
    do {                                                                         \
        const int _tk = (TK) & (NTK - 1);                                        \
        _Pragma("unroll")                                                        \
        for (int q = 0; q < 2; ++q) {                                            \
            const int seg  = wave * 2 + q;                                       \
            const int row0 = (H) * 32 + (seg & 3) * 8 + (seg >> 2) * 64;         \
            const u16* _g = B + (size_t)(bn + row0 + srow) * KD + _tk * 64 + scol; \
            gload_lds16(_g, Bs + (BOFF) + row0 * 64 + lane * 8);                 \
        }                                                                        \
    } while (0)

#define LOAD_A(MB, BOFF)                                                        \
    _Pragma("unroll")                                                           \
    for (int mm = 0; mm < 4; ++mm) {                                            \
        aR[mm][0] = __builtin_bit_cast(bf16x8, *(const us8*)(As + (BOFF) + aRow + ((MB) + mm) * 1024 + slot0)); \
        aR[mm][1] = __builtin_bit_cast(bf16x8, *(const us8*)(As + (BOFF) + aRow + ((MB) + mm) * 1024 + slot1)); \
    }

#define LOAD_B(DST, NB, BOFF)                                                   \
    _Pragma("unroll")                                                           \
    for (int nn = 0; nn < 2; ++nn) {                                            \
        DST[nn][0] = __builtin_bit_cast(bf16x8, *(const us8*)(Bs + (BOFF) + bRow + ((NB) + nn) * 1024 + slot0)); \
        DST[nn][1] = __builtin_bit_cast(bf16x8, *(const us8*)(Bs + (BOFF) + bRow + ((NB) + nn) * 1024 + slot1)); \
    }

// k-OUTER: 8 independent MFMAs between dependent acc updates; per-acc order
// k0-then-k1.
#define MFMA_Q(MB, NB, BREG)                                                    \
    do {                                                                        \
        __builtin_amdgcn_s_setprio(1);                                          \
        _Pragma("unroll")                                                       \
        for (int kk = 0; kk < 2; ++kk)                                          \
            _Pragma("unroll")                                                   \
            for (int mm = 0; mm < 4; ++mm)                                      \
                _Pragma("unroll")                                               \
                for (int nn = 0; nn < 2; ++nn)                                  \
                    acc[(MB)+mm][(NB)+nn] = __builtin_amdgcn_mfma_f32_16x16x32_bf16(aR[mm][kk], BREG[nn][kk], acc[(MB)+mm][(NB)+nn], 0, 0, 0); \
        __builtin_amdgcn_s_setprio(0);                                          \
    } while (0)

    // ---- prologue: 7 halves, steady-state mimic; vmcnt(6) completes tile 0
    STAGE_B(0, 0, 0);
    STAGE_A(0, 0, 0);
    STAGE_B(0, 1, 0);
    STAGE_A(0, 1, 0);
    STAGE_B(1, 0, 16384);
    STAGE_A(1, 0, 16384);
    STAGE_B(1, 1, 16384);
    WAITV(6);
    BAR();

    for (int t = 0; t < NTK; t += 2) {
        // ph1: compute t(buf0) q(m0-3,n0-1); stage A(t+1)h1' -> buf1
        LOAD_A(0, 0);
        LOAD_B(b01, 0, 0);
        STAGE_A(t + 1, 1, 16384);
        THROTTLE();            // 12-read phase: cap LDS queue before barrier
        BAR();
        MFMA_Q(0, 0, b01);
        BAR();
        // ph2: q(m0-3,n2-3); stage B(t+2)h0' -> buf0
        LOAD_B(b23, 2, 0);
        STAGE_B(t + 2, 0, 0);
        BAR();
        MFMA_Q(0, 2, b23);
        BAR();
        // ph3: q(m4-7,n2-3); stage A(t+2)h0' -> buf0
        LOAD_A(4, 0);
        STAGE_A(t + 2, 0, 0);
        BAR();
        MFMA_Q(4, 2, b23);
        BAR();
        // ph4: q(m4-7,n0-1); stage B(t+2)h1' -> buf0; vmcnt(6) completes tile t+1
        STAGE_B(t + 2, 1, 0);
        BAR();
        MFMA_Q(4, 0, b01);
        WAITV(6);
        BAR();
        // ph5: compute t+1(buf1) q(m0-3,n0-1); stage A(t+2)h1' -> buf0
        LOAD_A(0, 16384);
        LOAD_B(b01, 0, 16384);
        STAGE_A(t + 2, 1, 0);
        THROTTLE();
        BAR();
        MFMA_Q(0, 0, b01);
        BAR();
        // ph6: q(m0-3,n2-3); stage B(t+3)h0' -> buf1
        LOAD_B(b23, 2, 16384);
        STAGE_B(t + 3, 0, 16384);
        BAR();
        MFMA_Q(0, 2, b23);
        BAR();
        // ph7: q(m4-7,n2-3); stage A(t+3)h0' -> buf1
        LOAD_A(4, 16384);
        STAGE_A(t + 3, 0, 16384);
        BAR();
        MFMA_Q(4, 2, b23);
        BAR();
        // ph8: q(m4-7,n0-1); stage B(t+3)h1' -> buf1; vmcnt(6) completes tile t+2
        STAGE_B(t + 3, 1, 16384);
        BAR();
        MFMA_Q(4, 0, b01);
        WAITV(6);
        BAR();
    }

    asm volatile("s_waitcnt vmcnt(0)" ::: "memory");

    const int orow0 = wr * 128 + hi * 4;
    const int ocol0 = bn + wc * 64 + fr;
#pragma unroll
    for (int m = 0; m < 8; ++m)
#pragma unroll
        for (int n = 0; n < 4; ++n) {
            f32x4 v = acc[m][n];
#pragma unroll
            for (int rr = 0; rr < 4; ++rr) {
                size_t off = (size_t)(bm + orow0 + m * 16 + rr) * LDC + (ocol0 + n * 16);
                Cp[off] = bfbits(v[rr]);
            }
        }
#undef STAGE_A
#undef STAGE_B
#undef LOAD_A
#undef LOAD_B
#undef MFMA_Q
}

// ---------------------------------------------------------------------------
extern "C" void kernel_launch(void* const* d_in, const int* in_sizes, int n_in,
                              void* d_out, int out_size, void* d_ws, size_t ws_size,
                              hipStream_t stream) {
    const float* X = (const float*)d_in[0];
    float* Y = (float*)d_out;

    const size_t QM = (size_t)HDIM * HDIM;
    u16* Ce = (u16*)d_ws;
    u16* Co = Ce + QM;
    u16* Xe = Co + QM;
    u16* Xo = Xe + 2 * QM;
    u16* S  = Xo + 2 * QM;
    u16* D  = S + 2 * QM;
    u16* We = Xe;
    u16* Wo = Xo;
    u16* S2 = S;
    u16* D2 = D;

    k_prep<<<6144, 256, 0, stream>>>(Ce, Co, X, Xe, Xo);
    gemm256h<32, 4><<<256, 512, 0, stream>>>(Ce, Co, Xe, Xo, S);
    k_bfly1<<<4096, 256, 0, stream>>>(S, D, We, Wo);
    gemm256h<32, 3><<<256, 512, 0, stream>>>(We, Wo, Ce, Co, S2);
    k_bfly2<<<4096, 256, 0, stream>>>(S2, D2, Y);
}